// Round 3
// baseline (445.356 us; speedup 1.0000x reference)
//
#include <hip/hip_runtime.h>

// Recurrent ALIF 2D, forward. x:(8,64,16,16,256) f32, w_rec:(256,256) f32.
//
// R2 structure: ONE WAVE PER SITE, no LDS, no barriers.
//  - lane holds 4 contiguous features (float4 state): f = 4*lane .. 4*lane+3
//  - spike compaction = 4 ballots (mask_j bit l <-> feature/row 4l+j),
//    readfirstlane -> SGPR, scalar ctz iteration in (l,j) lex order
//    == ascending row k  => bit-identical summation order (R0: absmax 0.0)
//  - per active row: one global_load_dwordx4 (wave reads full 1KiB row,
//    L2-resident W), 4 fadds. Loads batched 8-deep, tail clamped to row 0
//    and discarded via fmaf(w, mu, rec) with mu in {0,1} (exact: fma*1==add,
//    fma*0 adds +0.0 which never changes rec since rec can't be -0.0).
//  - next-step x prefetched as dwordx4 before the gather.
// R1 lesson: previous 4-wave/site version was serial-latency-bound on
// 2 barriers + 2 LDS round-trips per step (VALUBusy fell 54->43% with no
// speedup). This removes that entire chain.

#define TSTEPS 64

__device__ __forceinline__ unsigned long long uniform_mask(unsigned long long m) {
    unsigned lo = __builtin_amdgcn_readfirstlane((unsigned)m);
    unsigned hi = __builtin_amdgcn_readfirstlane((unsigned)(m >> 32));
    return (((unsigned long long)hi) << 32) | lo;
}

__global__ __launch_bounds__(256) void alif_kernel(
    const float* __restrict__ x,
    const float* __restrict__ w_rec,
    const float* __restrict__ hp_d_p,
    const float* __restrict__ hp_adp_p,
    const float* __restrict__ hp_beta_p,
    float* __restrict__ out)
{
    const int lane = threadIdx.x & 63;
    const int wave = threadIdx.x >> 6;
    const int site = (int)(blockIdx.x << 2) | wave;   // 0..2047 = b*256 + hw
    const int b  = site >> 8;
    const int hw = site & 255;

    const float d    = hp_d_p[0];
    const float adp  = hp_adp_p[0];
    const float beta = hp_beta_p[0];

    // x[b, t, hw, f] flat index, f = 4*lane
    size_t xidx = (size_t)b * ((size_t)TSTEPS * 65536) + (size_t)hw * 256
                + ((size_t)lane << 2);
    const char* wb = (const char*)w_rec;
    const int fb16 = lane << 4;   // byte offset of lane's float4 within a row

    float4 v  = make_float4(0.f, 0.f, 0.f, 0.f);
    float4 th = make_float4(0.f, 0.f, 0.f, 0.f);
    float4 s  = make_float4(0.f, 0.f, 0.f, 0.f);
    float4 xt = *(const float4*)(x + xidx);

    for (int t = 0; t < TSTEPS; ++t) {
        // ---- wave-uniform spike masks: mask_j bit l <-> row 4l+j ----
        unsigned long long m0 = uniform_mask(__ballot(s.x != 0.f));
        unsigned long long m1 = uniform_mask(__ballot(s.y != 0.f));
        unsigned long long m2 = uniform_mask(__ballot(s.z != 0.f));
        unsigned long long m3 = uniform_mask(__ballot(s.w != 0.f));
        unsigned long long any = m0 | m1 | m2 | m3;

        // prefetch next x (independent of gather; hides HBM latency)
        size_t nidx = xidx + (t < TSTEPS - 1 ? (size_t)65536 : (size_t)0);
        float4 xn = *(const float4*)(x + nidx);

        float4 rec = make_float4(0.f, 0.f, 0.f, 0.f);

        // scalar extractor: emits active rows in ascending k = 4l+j
        int l = 0; unsigned nib = 0u;
        auto next = [&]() -> int {
            while (nib == 0u) {
                if (any == 0ull) return -1;
                l = (int)__builtin_ctzll(any); any &= any - 1ull;
                nib = (unsigned)(((m0 >> l) & 1ull)
                               | (((m1 >> l) & 1ull) << 1)
                               | (((m2 >> l) & 1ull) << 2)
                               | (((m3 >> l) & 1ull) << 3));
            }
            int j = __builtin_ctz(nib); nib &= nib - 1u;
            return (l << 2) + j;
        };

        int r0 = next();
        while (r0 >= 0) {
            int r1 = next(), r2 = next(), r3 = next();
            int r4 = next(), r5 = next(), r6 = next(), r7 = next();
            // clamp tail rows to 0 so all 8 loads issue unconditionally
            int a1 = r1 < 0 ? 0 : r1, a2 = r2 < 0 ? 0 : r2, a3 = r3 < 0 ? 0 : r3;
            int a4 = r4 < 0 ? 0 : r4, a5 = r5 < 0 ? 0 : r5, a6 = r6 < 0 ? 0 : r6;
            int a7 = r7 < 0 ? 0 : r7;
            float4 w0 = *(const float4*)(wb + ((r0 << 10) + fb16));
            float4 w1 = *(const float4*)(wb + ((a1 << 10) + fb16));
            float4 w2 = *(const float4*)(wb + ((a2 << 10) + fb16));
            float4 w3 = *(const float4*)(wb + ((a3 << 10) + fb16));
            float4 w4 = *(const float4*)(wb + ((a4 << 10) + fb16));
            float4 w5 = *(const float4*)(wb + ((a5 << 10) + fb16));
            float4 w6 = *(const float4*)(wb + ((a6 << 10) + fb16));
            float4 w7 = *(const float4*)(wb + ((a7 << 10) + fb16));
            float mu1 = r1 >= 0 ? 1.f : 0.f, mu2 = r2 >= 0 ? 1.f : 0.f;
            float mu3 = r3 >= 0 ? 1.f : 0.f, mu4 = r4 >= 0 ? 1.f : 0.f;
            float mu5 = r5 >= 0 ? 1.f : 0.f, mu6 = r6 >= 0 ? 1.f : 0.f;
            float mu7 = r7 >= 0 ? 1.f : 0.f;
            // ascending-k add chain (exact; see header)
            rec.x += w0.x; rec.y += w0.y; rec.z += w0.z; rec.w += w0.w;
            rec.x = fmaf(w1.x, mu1, rec.x); rec.y = fmaf(w1.y, mu1, rec.y);
            rec.z = fmaf(w1.z, mu1, rec.z); rec.w = fmaf(w1.w, mu1, rec.w);
            rec.x = fmaf(w2.x, mu2, rec.x); rec.y = fmaf(w2.y, mu2, rec.y);
            rec.z = fmaf(w2.z, mu2, rec.z); rec.w = fmaf(w2.w, mu2, rec.w);
            rec.x = fmaf(w3.x, mu3, rec.x); rec.y = fmaf(w3.y, mu3, rec.y);
            rec.z = fmaf(w3.z, mu3, rec.z); rec.w = fmaf(w3.w, mu3, rec.w);
            rec.x = fmaf(w4.x, mu4, rec.x); rec.y = fmaf(w4.y, mu4, rec.y);
            rec.z = fmaf(w4.z, mu4, rec.z); rec.w = fmaf(w4.w, mu4, rec.w);
            rec.x = fmaf(w5.x, mu5, rec.x); rec.y = fmaf(w5.y, mu5, rec.y);
            rec.z = fmaf(w5.z, mu5, rec.z); rec.w = fmaf(w5.w, mu5, rec.w);
            rec.x = fmaf(w6.x, mu6, rec.x); rec.y = fmaf(w6.y, mu6, rec.y);
            rec.z = fmaf(w6.z, mu6, rec.z); rec.w = fmaf(w6.w, mu6, rec.w);
            rec.x = fmaf(w7.x, mu7, rec.x); rec.y = fmaf(w7.y, mu7, rec.y);
            rec.z = fmaf(w7.z, mu7, rec.z); rec.w = fmaf(w7.w, mu7, rec.w);
            r0 = next();
        }

        // ---- elementwise ALIF update (same exprs as R0, absmax 0.0) ----
        float4 sn;
        {
            th.x = fmaf(th.x, adp, s.x * beta);
            float vn = fmaf(v.x, d, xt.x) + rec.x;
            float vt = 0.5f + th.x;
            sn.x = (vn - vt) > 0.f ? 1.f : 0.f;
            v.x = vn - sn.x * vt;
        }
        {
            th.y = fmaf(th.y, adp, s.y * beta);
            float vn = fmaf(v.y, d, xt.y) + rec.y;
            float vt = 0.5f + th.y;
            sn.y = (vn - vt) > 0.f ? 1.f : 0.f;
            v.y = vn - sn.y * vt;
        }
        {
            th.z = fmaf(th.z, adp, s.z * beta);
            float vn = fmaf(v.z, d, xt.z) + rec.z;
            float vt = 0.5f + th.z;
            sn.z = (vn - vt) > 0.f ? 1.f : 0.f;
            v.z = vn - sn.z * vt;
        }
        {
            th.w = fmaf(th.w, adp, s.w * beta);
            float vn = fmaf(v.w, d, xt.w) + rec.w;
            float vt = 0.5f + th.w;
            sn.w = (vn - vt) > 0.f ? 1.f : 0.f;
            v.w = vn - sn.w * vt;
        }
        s = sn;
        *(float4*)(out + xidx) = s;

        xidx = nidx;
        xt = xn;
    }
}

extern "C" void kernel_launch(void* const* d_in, const int* in_sizes, int n_in,
                              void* d_out, int out_size, void* d_ws, size_t ws_size,
                              hipStream_t stream) {
    const float* x       = (const float*)d_in[0];
    const float* w_rec   = (const float*)d_in[1];
    const float* hp_d    = (const float*)d_in[2];
    const float* hp_adp  = (const float*)d_in[3];
    const float* hp_beta = (const float*)d_in[4];
    // d_in[5] = hp_alpha: unused in forward
    float* out = (float*)d_out;

    // 2048 sites, 1 wave each, 4 waves per 256-thread block -> 512 blocks.
    alif_kernel<<<512, 256, 0, stream>>>(x, w_rec, hp_d, hp_adp, hp_beta, out);
}

// Round 8
// 329.743 us; speedup vs baseline: 1.3506x; 1.3506x over previous
//
#include <hip/hip_runtime.h>

// Recurrent ALIF 2D, forward. x:(8,64,16,16,256) f32, w_rec:(256,256) f32.
//
// Invariant (absmax 0.0 since R0): rec = sum of W rows with prev-spike==1,
// accumulated in ASCENDING row order, fp32; elementwise update expressions
// unchanged. Only load *sources* move (LDS copy of W = same bits).
//
// Structure (R2 was latency-serialized: VGPR=40 -> no loads in flight,
// 2 waves/SIMD, 287us):
//  - 512-thread block = 8 waves = 8 sites; 1 block/CU; grid 256.
//  - W rows 0..127 (128KB) staged in LDS once (+1 barrier). Row k<128 ->
//    ds_read_b128 (low latency, deep outstanding); k>=128 -> L2. Halves L2
//    traffic (the bandwidth wall) vs R2.
//  - Spike mask built in k-order: per-lane nibble of the float4 spikes,
//    shifted to 4*(lane&15), OR-reduced over 16-lane groups via shfl_xor,
//    readlane -> 4 SGPR words (bit k = spike[k]). Extraction = ctz+clear.
//  - Exact-count batches {8,4,2,1}: unconditional loads, 8 in flight,
//    zero clamp overload, zero wasted L2 bytes.
// (R7 = resubmit: R5/R6 benches failed on infra before ever running this.)

#define TSTEPS 64
typedef unsigned long long u64;

__device__ __forceinline__ u64 rl64(u64 v, int srcLane) {
    unsigned lo = __builtin_amdgcn_readlane((unsigned)v, srcLane);
    unsigned hi = __builtin_amdgcn_readlane((unsigned)(v >> 32), srcLane);
    return (((u64)hi) << 32) | lo;
}

// next set bit (ascending) of the 128-bit value (w0 low, w1 high); mutates.
__device__ __forceinline__ int nextbit(u64& w0, u64& w1) {
    if (w0) { int i = (int)__builtin_ctzll(w0); w0 &= w0 - 1ull; return i; }
    int i = (int)__builtin_ctzll(w1); w1 &= w1 - 1ull; return 64 + i;
}

__global__ __launch_bounds__(512) void alif_kernel(
    const float* __restrict__ x,
    const float* __restrict__ w_rec,
    const float* __restrict__ hp_d_p,
    const float* __restrict__ hp_adp_p,
    const float* __restrict__ hp_beta_p,
    float* __restrict__ out)
{
    const int tid  = threadIdx.x;
    const int lane = tid & 63;
    const int wave = tid >> 6;
    const int site = (int)(blockIdx.x << 3) | wave;   // 0..2047
    const int b  = site >> 8;
    const int hw = site & 255;

    const float d    = hp_d_p[0];
    const float adp  = hp_adp_p[0];
    const float beta = hp_beta_p[0];

    __shared__ float lw[32768];   // W rows 0..127 (128 KB)

    // ---- stage low half of W into LDS (coalesced float4) ----
    {
        const float4* src = (const float4*)w_rec;   // 8192 float4s
        float4* dst = (float4*)lw;
        #pragma unroll
        for (int i = 0; i < 16; ++i) dst[i * 512 + tid] = src[i * 512 + tid];
    }
    __syncthreads();

    size_t xidx = (size_t)b * ((size_t)TSTEPS * 65536) + (size_t)hw * 256
                + ((size_t)lane << 2);
    const int lof  = lane << 2;                         // float offset in LDS row
    const int fb16 = lane << 4;                         // byte offset in global row
    const char* wg = ((const char*)w_rec) + (128 << 10); // rows 128..255

    float4 v  = make_float4(0.f, 0.f, 0.f, 0.f);
    float4 th = make_float4(0.f, 0.f, 0.f, 0.f);
    float4 s  = make_float4(0.f, 0.f, 0.f, 0.f);
    float4 xt = *(const float4*)(x + xidx);

#define LROW(k) (*(const float4*)(lw + ((k) << 8) + lof))
#define GROW(k) (*(const float4*)(wg + (((size_t)(k)) << 10) + fb16))
#define ACC(q)  do { rec.x += (q).x; rec.y += (q).y; rec.z += (q).z; rec.w += (q).w; } while (0)

    for (int t = 0; t < TSTEPS; ++t) {
        // ---- k-order spike mask: bit k of (M0..M3) = spike[k] ----
        unsigned nib = (s.x != 0.f ? 1u : 0u) | (s.y != 0.f ? 2u : 0u)
                     | (s.z != 0.f ? 4u : 0u) | (s.w != 0.f ? 8u : 0u);
        u64 val = ((u64)nib) << ((lane & 15) << 2);
        val |= __shfl_xor(val, 1);
        val |= __shfl_xor(val, 2);
        val |= __shfl_xor(val, 4);
        val |= __shfl_xor(val, 8);   // 16-lane group OR-reduce
        u64 M0 = rl64(val, 0),  M1 = rl64(val, 16);
        u64 M2 = rl64(val, 32), M3 = rl64(val, 48);

        // prefetch next-step x
        size_t nidx = xidx + (t < TSTEPS - 1 ? (size_t)65536 : (size_t)0);
        float4 xn = *(const float4*)(x + nidx);

        float4 rec = make_float4(0.f, 0.f, 0.f, 0.f);

        // ---- phase 1: rows 0..127 from LDS (ascending k) ----
        {
            u64 a = M0, c = M1;
            int cnt = (int)__popcll(a) + (int)__popcll(c);
            while (cnt >= 8) {
                int k0 = nextbit(a, c); int k1 = nextbit(a, c);
                int k2 = nextbit(a, c); int k3 = nextbit(a, c);
                int k4 = nextbit(a, c); int k5 = nextbit(a, c);
                int k6 = nextbit(a, c); int k7 = nextbit(a, c);
                float4 q0 = LROW(k0), q1 = LROW(k1), q2 = LROW(k2), q3 = LROW(k3);
                float4 q4 = LROW(k4), q5 = LROW(k5), q6 = LROW(k6), q7 = LROW(k7);
                ACC(q0); ACC(q1); ACC(q2); ACC(q3);
                ACC(q4); ACC(q5); ACC(q6); ACC(q7);
                cnt -= 8;
            }
            if (cnt & 4) {
                int k0 = nextbit(a, c); int k1 = nextbit(a, c);
                int k2 = nextbit(a, c); int k3 = nextbit(a, c);
                float4 q0 = LROW(k0), q1 = LROW(k1), q2 = LROW(k2), q3 = LROW(k3);
                ACC(q0); ACC(q1); ACC(q2); ACC(q3);
            }
            if (cnt & 2) {
                int k0 = nextbit(a, c); int k1 = nextbit(a, c);
                float4 q0 = LROW(k0), q1 = LROW(k1);
                ACC(q0); ACC(q1);
            }
            if (cnt & 1) {
                int k0 = nextbit(a, c);
                float4 q0 = LROW(k0);
                ACC(q0);
            }
        }

        // ---- phase 2: rows 128..255 from global/L2 (ascending k) ----
        {
            u64 a = M2, c = M3;
            int cnt = (int)__popcll(a) + (int)__popcll(c);
            while (cnt >= 8) {
                int k0 = nextbit(a, c); int k1 = nextbit(a, c);
                int k2 = nextbit(a, c); int k3 = nextbit(a, c);
                int k4 = nextbit(a, c); int k5 = nextbit(a, c);
                int k6 = nextbit(a, c); int k7 = nextbit(a, c);
                float4 q0 = GROW(k0), q1 = GROW(k1), q2 = GROW(k2), q3 = GROW(k3);
                float4 q4 = GROW(k4), q5 = GROW(k5), q6 = GROW(k6), q7 = GROW(k7);
                ACC(q0); ACC(q1); ACC(q2); ACC(q3);
                ACC(q4); ACC(q5); ACC(q6); ACC(q7);
                cnt -= 8;
            }
            if (cnt & 4) {
                int k0 = nextbit(a, c); int k1 = nextbit(a, c);
                int k2 = nextbit(a, c); int k3 = nextbit(a, c);
                float4 q0 = GROW(k0), q1 = GROW(k1), q2 = GROW(k2), q3 = GROW(k3);
                ACC(q0); ACC(q1); ACC(q2); ACC(q3);
            }
            if (cnt & 2) {
                int k0 = nextbit(a, c); int k1 = nextbit(a, c);
                float4 q0 = GROW(k0), q1 = GROW(k1);
                ACC(q0); ACC(q1);
            }
            if (cnt & 1) {
                int k0 = nextbit(a, c);
                float4 q0 = GROW(k0);
                ACC(q0);
            }
        }

        // ---- elementwise ALIF update (expressions unchanged since R0) ----
        float4 sn;
        th.x = fmaf(th.x, adp, s.x * beta);
        { float vn = fmaf(v.x, d, xt.x) + rec.x; float vt = 0.5f + th.x;
          sn.x = (vn - vt) > 0.f ? 1.f : 0.f; v.x = vn - sn.x * vt; }
        th.y = fmaf(th.y, adp, s.y * beta);
        { float vn = fmaf(v.y, d, xt.y) + rec.y; float vt = 0.5f + th.y;
          sn.y = (vn - vt) > 0.f ? 1.f : 0.f; v.y = vn - sn.y * vt; }
        th.z = fmaf(th.z, adp, s.z * beta);
        { float vn = fmaf(v.z, d, xt.z) + rec.z; float vt = 0.5f + th.z;
          sn.z = (vn - vt) > 0.f ? 1.f : 0.f; v.z = vn - sn.z * vt; }
        th.w = fmaf(th.w, adp, s.w * beta);
        { float vn = fmaf(v.w, d, xt.w) + rec.w; float vt = 0.5f + th.w;
          sn.w = (vn - vt) > 0.f ? 1.f : 0.f; v.w = vn - sn.w * vt; }
        s = sn;
        *(float4*)(out + xidx) = s;

        xidx = nidx;
        xt = xn;
    }
#undef LROW
#undef GROW
#undef ACC
}

extern "C" void kernel_launch(void* const* d_in, const int* in_sizes, int n_in,
                              void* d_out, int out_size, void* d_ws, size_t ws_size,
                              hipStream_t stream) {
    const float* x       = (const float*)d_in[0];
    const float* w_rec   = (const float*)d_in[1];
    const float* hp_d    = (const float*)d_in[2];
    const float* hp_adp  = (const float*)d_in[3];
    const float* hp_beta = (const float*)d_in[4];
    // d_in[5] = hp_alpha: unused in forward
    float* out = (float*)d_out;

    // 2048 sites = 256 blocks x 8 waves (1 site/wave); 1 block/CU (128KB LDS).
    alif_kernel<<<256, 512, 0, stream>>>(x, w_rec, hp_d, hp_adp, hp_beta, out);
}